// Round 6
// baseline (217.581 us; speedup 1.0000x reference)
//
#include <hip/hip_runtime.h>
#include <math.h>

#define NN 1024     // entities
#define HD 128      // hidden dim
#define NH 8        // heads
#define CH 16       // dim per head
#define NLAYERS 3

#define TT 8        // targets per attention block
#define SF 1040     // s_tile f32 row stride: 4160B; mod 128B = 64 -> adjacent rows shift 16 banks (2-way, free)
#define ALP 130     // al row stride (floats): 130%32=2 -> f2 reads across 32 rows hit 16 banks 2-way (free)
#define PR 8        // rows per block in k_proj / k_edge_ab

__device__ __forceinline__ float bf16_to_f32(unsigned short u) {
    union { unsigned int i; float f; } x; x.i = ((unsigned int)u) << 16; return x.f;
}
__device__ __forceinline__ unsigned short f32_to_bf16(float f) {
    union { float f; unsigned int i; } x; x.f = f;
    const unsigned int r = x.i + 0x7FFFu + ((x.i >> 16) & 1u);   // RNE
    return (unsigned short)(r >> 16);
}

// ---------------- K1: a = x@W1[:128], b = x@W1[128:] + b1 (8 rows/block) ----------------
__global__ __launch_bounds__(256) void k_edge_ab(
        const float* __restrict__ x, const float* __restrict__ W1,
        const float* __restrict__ b1, float* __restrict__ a, float* __restrict__ b) {
    __shared__ float xr[PR][HD];
    const int r0 = blockIdx.x * PR, t = threadIdx.x;
    {   // stage 8x128 f32 as 256 float4s, one per thread
        const int row = t >> 5, col = (t & 31) * 4;
        *(float4*)&xr[row][col] = *(const float4*)&x[(r0 + row) * HD + col];
    }
    __syncthreads();
    const int c = t & 127;
    const int half = t >> 7;                 // 0 -> a, 1 -> b
    const float* w = W1 + half * HD * HD + c;
    const float bias = half ? b1[c] : 0.f;   // fold b1 into b
    float acc[PR];
    #pragma unroll
    for (int r = 0; r < PR; ++r) acc[r] = bias;
    #pragma unroll 4
    for (int kk = 0; kk < HD; ++kk) {
        const float wv = w[kk * HD];
        #pragma unroll
        for (int r = 0; r < PR; ++r) acc[r] = fmaf(xr[r][kk], wv, acc[r]);
    }
    float* dst = half ? b : a;
    #pragma unroll
    for (int r = 0; r < PR; ++r) dst[(r0 + r) * HD + c] = acc[r];
}

// ---------------- K2: wm[t][s] = bf16( sign(mask) * sigmoid(logit[s][t]) ) ----------------
__global__ __launch_bounds__(256) void k_edge_w(
        const float* __restrict__ a, const float* __restrict__ bb,
        const float* __restrict__ W2, const float* __restrict__ b2,
        unsigned short* __restrict__ wm) {
    __shared__ float al[32][ALP];
    __shared__ float bl[16][HD];
    const int t = threadIdx.x;
    const int s0 = blockIdx.x * 32, t0 = blockIdx.y * 16;
    // stage al: 32x128 = 2048 float2s
    for (int ii = t; ii < 2048; ii += 256) {
        const int row = ii >> 6, col = (ii & 63) * 2;
        *(float2*)&al[row][col] = *(const float2*)&a[(s0 + row) * HD + col];
    }
    // stage bl: 16x128 = 512 float4s
    for (int ii = t; ii < 512; ii += 256) {
        const int row = ii >> 5, col = (ii & 31) * 4;
        *(float4*)&bl[row][col] = *(const float4*)&bb[(t0 + row) * HD + col];
    }
    __syncthreads();
    const int s = t & 31, tt = t >> 5;
    float acc0 = 0.f, acc1 = 0.f;
    #pragma unroll 2
    for (int h4 = 0; h4 < HD; h4 += 4) {
        const float4 w2 = *(const float4*)&W2[h4];          // uniform -> s_load_dwordx4
        const float2 avA = *(const float2*)&al[s][h4];
        const float2 avB = *(const float2*)&al[s][h4 + 2];
        const float4 b0v = *(const float4*)&bl[tt][h4];
        const float4 b1v = *(const float4*)&bl[tt + 8][h4];
        acc0 = fmaf(fmaxf(avA.x + b0v.x, 0.f), w2.x, acc0);
        acc0 = fmaf(fmaxf(avA.y + b0v.y, 0.f), w2.y, acc0);
        acc0 = fmaf(fmaxf(avB.x + b0v.z, 0.f), w2.z, acc0);
        acc0 = fmaf(fmaxf(avB.y + b0v.w, 0.f), w2.w, acc0);
        acc1 = fmaf(fmaxf(avA.x + b1v.x, 0.f), w2.x, acc1);
        acc1 = fmaf(fmaxf(avA.y + b1v.y, 0.f), w2.y, acc1);
        acc1 = fmaf(fmaxf(avB.x + b1v.z, 0.f), w2.z, acc1);
        acc1 = fmaf(fmaxf(avB.y + b1v.w, 0.f), w2.w, acc1);
    }
    const float bias = b2[0];
    const float l0 = acc0 + bias, l1 = acc1 + bias;
    const float w0 = 1.f / (1.f + __expf(-l0));
    const float w1 = 1.f / (1.f + __expf(-l1));
    wm[(t0 + tt    ) * NN + s0 + s] = f32_to_bf16((l0 > 0.f) ? w0 : -w0);   // sign encodes mask
    wm[(t0 + tt + 8) * NN + s0 + s] = f32_to_bf16((l1 > 0.f) ? w1 : -w1);
}

// ---------------- K3: projections q,k,v ([h][n][c]) + skip; 8 rows/block ----------------
__global__ __launch_bounds__(256) void k_proj(
        const float* __restrict__ x,
        const float* __restrict__ Wq, const float* __restrict__ bq,
        const float* __restrict__ Wk, const float* __restrict__ bk,
        const float* __restrict__ Wv, const float* __restrict__ bv,
        const float* __restrict__ Wsk, const float* __restrict__ bsk,
        float* __restrict__ q, float* __restrict__ k,
        float* __restrict__ v, float* __restrict__ skip) {
    __shared__ float xr[PR][HD];
    const int r0 = blockIdx.x * PR, t = threadIdx.x;
    {
        const int row = t >> 5, col = (t & 31) * 4;
        *(float4*)&xr[row][col] = *(const float4*)&x[(r0 + row) * HD + col];
    }
    __syncthreads();
    const int c = t & 127;
    const bool lo = t < 128;                 // lo: q&k, hi: v&skip
    const float* WA = (lo ? Wq : Wv) + c;
    const float* WB = (lo ? Wk : Wsk) + c;
    const float bA = lo ? bq[c] : bv[c];
    const float bB = lo ? bk[c] : bsk[c];
    float accA[PR], accB[PR];
    #pragma unroll
    for (int r = 0; r < PR; ++r) { accA[r] = bA; accB[r] = bB; }
    #pragma unroll 4
    for (int kk = 0; kk < HD; ++kk) {
        const float wa = WA[kk * HD];
        const float wb = WB[kk * HD];
        #pragma unroll
        for (int r = 0; r < PR; ++r) {
            const float xv = xr[r][kk];
            accA[r] = fmaf(xv, wa, accA[r]);
            accB[r] = fmaf(xv, wb, accB[r]);
        }
    }
    #pragma unroll
    for (int r = 0; r < PR; ++r) {
        const int row = r0 + r;
        const int hnc = (c >> 4) * (NN * CH) + row * CH + (c & 15);
        if (lo) { q[hnc] = accA[r]; k[hnc] = accB[r]; }
        else    { v[hnc] = accA[r]; skip[row * HD + c] = accB[r]; }
    }
}

// ---------------- K4: fused attention, one (head, 8-target tile); 2 barriers ----------------
__global__ __launch_bounds__(256) void k_attn(
        const float* __restrict__ q, const float* __restrict__ k,
        const float* __restrict__ v, const float* __restrict__ skip,
        const unsigned short* __restrict__ wm, const float* __restrict__ We,
        float* __restrict__ x) {
    __shared__ float s_tile[TT][SF];   // 33.3 KB
    __shared__ float q_l[TT][CH];      // q * 0.25 (scale folded)
    __shared__ float mpart[4][TT];     // per-wave partial row maxima
    const int h  = blockIdx.x;
    const int i0 = blockIdx.y * TT;
    const int t  = threadIdx.x;

    if (t < TT * CH) q_l[t >> 4][t & 15] = q[h * (NN * CH) + (i0 + (t >> 4)) * CH + (t & 15)] * 0.25f;
    __syncthreads();

    // ---- phase 1: logits + online row max. 2 groups x 128 threads; group g owns rows g*4..g*4+3.
    const int g  = t >> 7;             // 0/1
    const int lj = t & 127;
    float qr[4][CH], qe[4];
    #pragma unroll
    for (int i = 0; i < 4; ++i) {
        float sv = 0.f;
        #pragma unroll
        for (int c = 0; c < CH; ++c) {
            qr[i][c] = q_l[g * 4 + i][c];
            sv = fmaf(qr[i][c], We[h * CH + c], sv);   // We uniform -> scalar loads
        }
        qe[i] = sv;                    // carries the 0.25 scale
    }
    const float* kh = k + h * (NN * CH);
    float mloc[4] = {-1e30f, -1e30f, -1e30f, -1e30f};
    #pragma unroll 1
    for (int p = 0; p < 8; ++p) {
        const int j = lj + 128 * p;
        const float4* kp = (const float4*)(kh + j * CH);
        const float4 r0 = kp[0], r1 = kp[1], r2 = kp[2], r3 = kp[3];
        const float kr[CH] = {r0.x, r0.y, r0.z, r0.w, r1.x, r1.y, r1.z, r1.w,
                              r2.x, r2.y, r2.z, r2.w, r3.x, r3.y, r3.z, r3.w};
        #pragma unroll
        for (int i = 0; i < 4; ++i) {
            float dot = 0.f;
            #pragma unroll
            for (int c = 0; c < CH; ++c) dot = fmaf(qr[i][c], kr[c], dot);
            const float wv = bf16_to_f32(wm[(i0 + g * 4 + i) * NN + j]);   // sign = mask
            float sv = dot + qe[i] * fabsf(wv);
            sv = (wv > 0.f) ? sv : -1e30f;
            s_tile[g * 4 + i][j] = sv;
            mloc[i] = fmaxf(mloc[i], sv);
        }
    }
    // wave-level butterfly max, then cross-wave via LDS
    #pragma unroll
    for (int off = 1; off < 64; off <<= 1) {
        #pragma unroll
        for (int i = 0; i < 4; ++i) mloc[i] = fmaxf(mloc[i], __shfl_xor(mloc[i], off));
    }
    if ((t & 63) == 0) {
        const int w = t >> 6;
        #pragma unroll
        for (int i = 0; i < 4; ++i) mpart[w][g * 4 + i] = mloc[i];
    }
    __syncthreads();

    // ---- phase 2 (fused): single scan: p = exp(s-m), accumulate o, sum, aw. thread = (i, jb, c4).
    const int i3 = t >> 5, jb = (t >> 2) & 7, c4 = t & 3;
    const int gr = i3 >> 2;
    const float m = fmaxf(mpart[2 * gr][i3], mpart[2 * gr + 1][i3]);
    const bool live = m > -1e29f;
    const float* vh = v + h * (NN * CH) + c4 * 4;
    const unsigned short* wrow = wm + (i0 + i3) * NN;
    float o0 = 0.f, o1 = 0.f, o2 = 0.f, o3 = 0.f, sum = 0.f, aw = 0.f;
    #pragma unroll 2
    for (int gg = 0; gg < 32; ++gg) {
        const int j0 = jb * 4 + 32 * gg;
        const float4 sv4 = *(const float4*)&s_tile[i3][j0];
        const ushort4 w4 = *(const ushort4*)&wrow[j0];
        const float p0 = (sv4.x > -1e29f) ? __expf(sv4.x - m) : 0.f;
        const float p1 = (sv4.y > -1e29f) ? __expf(sv4.y - m) : 0.f;
        const float p2 = (sv4.z > -1e29f) ? __expf(sv4.z - m) : 0.f;
        const float p3 = (sv4.w > -1e29f) ? __expf(sv4.w - m) : 0.f;
        sum += (p0 + p1) + (p2 + p3);
        aw = fmaf(p0, fabsf(bf16_to_f32(w4.x)), aw);
        aw = fmaf(p1, fabsf(bf16_to_f32(w4.y)), aw);
        aw = fmaf(p2, fabsf(bf16_to_f32(w4.z)), aw);
        aw = fmaf(p3, fabsf(bf16_to_f32(w4.w)), aw);
        const float4 v0 = *(const float4*)&vh[(j0 + 0) * CH];
        const float4 v1 = *(const float4*)&vh[(j0 + 1) * CH];
        const float4 v2 = *(const float4*)&vh[(j0 + 2) * CH];
        const float4 v3 = *(const float4*)&vh[(j0 + 3) * CH];
        o0 = fmaf(p0, v0.x, o0); o1 = fmaf(p0, v0.y, o1); o2 = fmaf(p0, v0.z, o2); o3 = fmaf(p0, v0.w, o3);
        o0 = fmaf(p1, v1.x, o0); o1 = fmaf(p1, v1.y, o1); o2 = fmaf(p1, v1.z, o2); o3 = fmaf(p1, v1.w, o3);
        o0 = fmaf(p2, v2.x, o0); o1 = fmaf(p2, v2.y, o1); o2 = fmaf(p2, v2.z, o2); o3 = fmaf(p2, v2.w, o3);
        o0 = fmaf(p3, v3.x, o0); o1 = fmaf(p3, v3.y, o1); o2 = fmaf(p3, v3.z, o2); o3 = fmaf(p3, v3.w, o3);
    }
    #pragma unroll
    for (int off = 4; off <= 16; off <<= 1) {
        o0  += __shfl_xor(o0, off);
        o1  += __shfl_xor(o1, off);
        o2  += __shfl_xor(o2, off);
        o3  += __shfl_xor(o3, off);
        sum += __shfl_xor(sum, off);
        aw  += __shfl_xor(aw, off);
    }
    if (jb == 0) {
        const float inv = live ? 1.f / sum : 0.f;
        const float awv = aw * inv;
        const int idx = (i0 + i3) * HD + h * CH + c4 * 4;
        const float4 we4 = *(const float4*)&We[h * CH + c4 * 4];
        const float4 xo = *(const float4*)&x[idx];
        const float4 so = *(const float4*)&skip[idx];
        float4 o;
        o.x = xo.x + so.x + o0 * inv + awv * we4.x;
        o.y = xo.y + so.y + o1 * inv + awv * we4.y;
        o.z = xo.z + so.z + o2 * inv + awv * we4.z;
        o.w = xo.w + so.w + o3 * inv + awv * we4.w;
        *(float4*)&x[idx] = o;       // slice owned exclusively by this block
    }
}

// ---------------- launch ----------------
extern "C" void kernel_launch(void* const* d_in, const int* in_sizes, int n_in,
                              void* d_out, int out_size, void* d_ws, size_t ws_size,
                              hipStream_t stream) {
    const float* ent = (const float*)d_in[2];
    const float* W1  = (const float*)d_in[3];
    const float* b1  = (const float*)d_in[4];
    const float* W2  = (const float*)d_in[5];
    const float* b2  = (const float*)d_in[6];
    const float* Wq  = (const float*)d_in[7];
    const float* bq  = (const float*)d_in[8];
    const float* Wk  = (const float*)d_in[9];
    const float* bk  = (const float*)d_in[10];
    const float* Wv  = (const float*)d_in[11];
    const float* bv  = (const float*)d_in[12];
    const float* We  = (const float*)d_in[13];
    const float* Ws  = (const float*)d_in[14];
    const float* bs  = (const float*)d_in[15];

    unsigned short* wm = (unsigned short*)d_ws;   // [1024][1024] bf16, sign = mask (2 MB)
    float* fb = (float*)d_ws + (NN * NN / 2);     // float area after wm
    float* q  = fb;                               // [8][1024][16]  (reused as 'a' before layers)
    float* k  = q + NN * HD;                      //                (reused as 'b')
    float* v  = k + NN * HD;                      // [8][1024][16]
    float* sk = v + NN * HD;
    float* x  = (float*)d_out;                    // running entity state

    hipMemcpyAsync(x, ent, NN * HD * sizeof(float), hipMemcpyDeviceToDevice, stream);

    k_edge_ab<<<NN / PR, 256, 0, stream>>>(ent, W1, b1, q /*a*/, k /*b*/);
    k_edge_w<<<dim3(32, 64), 256, 0, stream>>>(q, k, W2, b2, wm);

    for (int l = 0; l < NLAYERS; ++l) {
        k_proj<<<NN / PR, 256, 0, stream>>>(x,
            Wq + l * HD * HD, bq + l * HD, Wk + l * HD * HD, bk + l * HD,
            Wv + l * HD * HD, bv + l * HD, Ws + l * HD * HD, bs + l * HD,
            q, k, v, sk);
        k_attn<<<dim3(NH, NN / TT), 256, 0, stream>>>(q, k, v, sk, wm, We + l * HD, x);
    }
}

// Round 7
// 132.579 us; speedup vs baseline: 1.6411x; 1.6411x over previous
//
#include <hip/hip_runtime.h>
#include <math.h>

#define NN 1024     // entities
#define HD 128      // hidden dim
#define NH 8        // heads
#define CH 16       // dim per head
#define NLAYERS 3

#define TT 8        // targets per attention block
#define SF 1040     // s_tile f32 row stride: 4160B; mod 128B = 64 -> adjacent rows shift 16 banks (2-way, free)
#define ALP 130     // al row stride (floats): 130%32=2 -> f2 reads across 32 rows hit 16 banks 2-way (free)
#define PBM 4       // k_proj rows per block
#define ABM 2       // k_edge_ab rows per block

__device__ __forceinline__ float bf16_to_f32(unsigned short u) {
    union { unsigned int i; float f; } x; x.i = ((unsigned int)u) << 16; return x.f;
}
__device__ __forceinline__ unsigned short f32_to_bf16(float f) {
    union { float f; unsigned int i; } x; x.f = f;
    const unsigned int r = x.i + 0x7FFFu + ((x.i >> 16) & 1u);   // RNE
    return (unsigned short)(r >> 16);
}

// ---------------- K1: a = x@W1[:128], b = x@W1[128:] + b1 ----------------
// grid (NN/ABM, 2): by=0 -> a (W1 first half), by=1 -> b (+bias b1). 1024 blocks, 4/CU.
__global__ __launch_bounds__(256) void k_edge_ab(
        const float* __restrict__ x, const float* __restrict__ W1,
        const float* __restrict__ b1, float* __restrict__ a, float* __restrict__ b) {
    __shared__ float xt[HD][ABM];        // x transposed: xt[kk][r]
    __shared__ float red[2][ABM][HD];    // kk-group partials
    const int r0 = blockIdx.x * ABM;
    const int cb = blockIdx.y;           // 0 -> a, 1 -> b
    const int t  = threadIdx.x;
    xt[t & 127][t >> 7] = x[(r0 + (t >> 7)) * HD + (t & 127)];
    __syncthreads();
    const int c = t & 127, g = t >> 7;   // col, kk-group
    const float* wp = W1 + cb * HD * HD + g * 64 * HD + c;
    const float* xp = &xt[g * 64][0];
    float a0 = 0.f, a1 = 0.f;
    #pragma unroll 8
    for (int kk = 0; kk < 64; ++kk) {
        const float wv = wp[kk * HD];                         // coalesced 256B/wave
        const float2 xv = *(const float2*)&xp[kk * ABM];      // uniform ds_read_b64 (broadcast)
        a0 = fmaf(xv.x, wv, a0);
        a1 = fmaf(xv.y, wv, a1);
    }
    red[g][0][c] = a0; red[g][1][c] = a1;
    __syncthreads();
    if (t < HD) {
        float* dst = cb ? b : a;
        const float bias = cb ? b1[t] : 0.f;                  // fold b1 into b
        #pragma unroll
        for (int r = 0; r < ABM; ++r)
            dst[(r0 + r) * HD + t] = red[0][r][t] + red[1][r][t] + bias;
    }
}

// ---------------- K2: wm[t][s] = bf16( sign(mask) * sigmoid(logit[s][t]) ) ----------------
__global__ __launch_bounds__(256) void k_edge_w(
        const float* __restrict__ a, const float* __restrict__ bb,
        const float* __restrict__ W2, const float* __restrict__ b2,
        unsigned short* __restrict__ wm) {
    __shared__ float al[32][ALP];
    __shared__ float bl[16][HD];
    const int t = threadIdx.x;
    const int s0 = blockIdx.x * 32, t0 = blockIdx.y * 16;
    for (int ii = t; ii < 2048; ii += 256) {
        const int row = ii >> 6, col = (ii & 63) * 2;
        *(float2*)&al[row][col] = *(const float2*)&a[(s0 + row) * HD + col];
    }
    for (int ii = t; ii < 512; ii += 256) {
        const int row = ii >> 5, col = (ii & 31) * 4;
        *(float4*)&bl[row][col] = *(const float4*)&bb[(t0 + row) * HD + col];
    }
    __syncthreads();
    const int s = t & 31, tt = t >> 5;
    float acc0 = 0.f, acc1 = 0.f;
    #pragma unroll 2
    for (int h4 = 0; h4 < HD; h4 += 4) {
        const float4 w2 = *(const float4*)&W2[h4];          // uniform -> s_load_dwordx4
        const float2 avA = *(const float2*)&al[s][h4];
        const float2 avB = *(const float2*)&al[s][h4 + 2];
        const float4 b0v = *(const float4*)&bl[tt][h4];
        const float4 b1v = *(const float4*)&bl[tt + 8][h4];
        acc0 = fmaf(fmaxf(avA.x + b0v.x, 0.f), w2.x, acc0);
        acc0 = fmaf(fmaxf(avA.y + b0v.y, 0.f), w2.y, acc0);
        acc0 = fmaf(fmaxf(avB.x + b0v.z, 0.f), w2.z, acc0);
        acc0 = fmaf(fmaxf(avB.y + b0v.w, 0.f), w2.w, acc0);
        acc1 = fmaf(fmaxf(avA.x + b1v.x, 0.f), w2.x, acc1);
        acc1 = fmaf(fmaxf(avA.y + b1v.y, 0.f), w2.y, acc1);
        acc1 = fmaf(fmaxf(avB.x + b1v.z, 0.f), w2.z, acc1);
        acc1 = fmaf(fmaxf(avB.y + b1v.w, 0.f), w2.w, acc1);
    }
    const float bias = b2[0];
    const float l0 = acc0 + bias, l1 = acc1 + bias;
    const float w0 = 1.f / (1.f + __expf(-l0));
    const float w1 = 1.f / (1.f + __expf(-l1));
    wm[(t0 + tt    ) * NN + s0 + s] = f32_to_bf16((l0 > 0.f) ? w0 : -w0);   // sign encodes mask
    wm[(t0 + tt + 8) * NN + s0 + s] = f32_to_bf16((l1 > 0.f) ? w1 : -w1);
}

// ---------------- K3: projections q,k,v ([h][n][c]) + skip ----------------
// grid (NN/PBM, 4): by selects matrix {Wq,Wk,Wv,Ws}. 1024 blocks, 4/CU, kk-split x2.
__global__ __launch_bounds__(256) void k_proj(
        const float* __restrict__ x,
        const float* __restrict__ Wq, const float* __restrict__ bq,
        const float* __restrict__ Wk, const float* __restrict__ bk,
        const float* __restrict__ Wv, const float* __restrict__ bv,
        const float* __restrict__ Wsk, const float* __restrict__ bsk,
        float* __restrict__ q, float* __restrict__ k,
        float* __restrict__ v, float* __restrict__ skip) {
    __shared__ float xt[HD][PBM];        // x transposed: xt[kk][r]
    __shared__ float red[2][PBM][HD];    // kk-group partials
    const int r0 = blockIdx.x * PBM;
    const int cb = blockIdx.y;           // 0..3 -> q,k,v,skip
    const int t  = threadIdx.x;
    {   // stage 4x128 transposed (one-time; write conflicts negligible)
        const int r = t >> 6, c2 = (t & 63) * 2;
        const float2 xv = *(const float2*)&x[(r0 + r) * HD + c2];
        xt[c2][r] = xv.x; xt[c2 + 1][r] = xv.y;
    }
    __syncthreads();
    const int c = t & 127, g = t >> 7;   // col within matrix, kk-group
    const float* W = (cb == 0) ? Wq : (cb == 1) ? Wk : (cb == 2) ? Wv : Wsk;
    const float* wp = W + g * 64 * HD + c;
    const float* xp = &xt[g * 64][0];
    float a0 = 0.f, a1 = 0.f, a2 = 0.f, a3 = 0.f;
    #pragma unroll 8
    for (int kk = 0; kk < 64; ++kk) {
        const float wv = wp[kk * HD];                         // coalesced 256B/wave
        const float4 xv = *(const float4*)&xp[kk * PBM];      // uniform ds_read_b128 (broadcast)
        a0 = fmaf(xv.x, wv, a0);
        a1 = fmaf(xv.y, wv, a1);
        a2 = fmaf(xv.z, wv, a2);
        a3 = fmaf(xv.w, wv, a3);
    }
    red[g][0][c] = a0; red[g][1][c] = a1; red[g][2][c] = a2; red[g][3][c] = a3;
    __syncthreads();
    if (t < HD) {
        const float* bptr = (cb == 0) ? bq : (cb == 1) ? bk : (cb == 2) ? bv : bsk;
        const float bias = bptr[t];
        #pragma unroll
        for (int r = 0; r < PBM; ++r) {
            const float val = red[0][r][t] + red[1][r][t] + bias;
            const int row = r0 + r;
            if (cb == 3) {
                skip[row * HD + t] = val;
            } else {
                const int hnc = (t >> 4) * (NN * CH) + row * CH + (t & 15);
                ((cb == 0) ? q : (cb == 1) ? k : v)[hnc] = val;
            }
        }
    }
}

// ---------------- K4: fused attention, one (head, 8-target tile); 2 barriers ----------------
__global__ __launch_bounds__(256) void k_attn(
        const float* __restrict__ q, const float* __restrict__ k,
        const float* __restrict__ v, const float* __restrict__ skip,
        const unsigned short* __restrict__ wm, const float* __restrict__ We,
        float* __restrict__ x) {
    __shared__ float s_tile[TT][SF];   // 33.3 KB
    __shared__ float q_l[TT][CH];      // q * 0.25 (scale folded)
    __shared__ float mpart[4][TT];     // per-wave partial row maxima
    const int h  = blockIdx.x;
    const int i0 = blockIdx.y * TT;
    const int t  = threadIdx.x;

    if (t < TT * CH) q_l[t >> 4][t & 15] = q[h * (NN * CH) + (i0 + (t >> 4)) * CH + (t & 15)] * 0.25f;
    __syncthreads();

    // ---- phase 1: logits + online row max. 2 groups x 128 threads; group g owns rows g*4..g*4+3.
    const int g  = t >> 7;             // 0/1
    const int lj = t & 127;
    float qr[4][CH], qe[4];
    #pragma unroll
    for (int i = 0; i < 4; ++i) {
        float sv = 0.f;
        #pragma unroll
        for (int c = 0; c < CH; ++c) {
            qr[i][c] = q_l[g * 4 + i][c];
            sv = fmaf(qr[i][c], We[h * CH + c], sv);   // We uniform -> scalar loads
        }
        qe[i] = sv;                    // carries the 0.25 scale
    }
    const float* kh = k + h * (NN * CH);
    float mloc[4] = {-1e30f, -1e30f, -1e30f, -1e30f};
    #pragma unroll 1
    for (int p = 0; p < 8; ++p) {
        const int j = lj + 128 * p;
        const float4* kp = (const float4*)(kh + j * CH);
        const float4 r0 = kp[0], r1 = kp[1], r2 = kp[2], r3 = kp[3];
        const float kr[CH] = {r0.x, r0.y, r0.z, r0.w, r1.x, r1.y, r1.z, r1.w,
                              r2.x, r2.y, r2.z, r2.w, r3.x, r3.y, r3.z, r3.w};
        #pragma unroll
        for (int i = 0; i < 4; ++i) {
            float dot = 0.f;
            #pragma unroll
            for (int c = 0; c < CH; ++c) dot = fmaf(qr[i][c], kr[c], dot);
            const float wv = bf16_to_f32(wm[(i0 + g * 4 + i) * NN + j]);   // sign = mask
            float sv = dot + qe[i] * fabsf(wv);
            sv = (wv > 0.f) ? sv : -1e30f;
            s_tile[g * 4 + i][j] = sv;
            mloc[i] = fmaxf(mloc[i], sv);
        }
    }
    // wave-level butterfly max, then cross-wave via LDS
    #pragma unroll
    for (int off = 1; off < 64; off <<= 1) {
        #pragma unroll
        for (int i = 0; i < 4; ++i) mloc[i] = fmaxf(mloc[i], __shfl_xor(mloc[i], off));
    }
    if ((t & 63) == 0) {
        const int w = t >> 6;
        #pragma unroll
        for (int i = 0; i < 4; ++i) mpart[w][g * 4 + i] = mloc[i];
    }
    __syncthreads();

    // ---- phase 2 (fused): single scan: p = exp(s-m), accumulate o, sum, aw. thread = (i, jb, c4).
    const int i3 = t >> 5, jb = (t >> 2) & 7, c4 = t & 3;
    const int gr = i3 >> 2;
    const float m = fmaxf(mpart[2 * gr][i3], mpart[2 * gr + 1][i3]);
    const bool live = m > -1e29f;
    const float* vh = v + h * (NN * CH) + c4 * 4;
    const unsigned short* wrow = wm + (i0 + i3) * NN;
    float o0 = 0.f, o1 = 0.f, o2 = 0.f, o3 = 0.f, sum = 0.f, aw = 0.f;
    #pragma unroll 2
    for (int gg = 0; gg < 32; ++gg) {
        const int j0 = jb * 4 + 32 * gg;
        const float4 sv4 = *(const float4*)&s_tile[i3][j0];
        const ushort4 w4 = *(const ushort4*)&wrow[j0];
        const float p0 = (sv4.x > -1e29f) ? __expf(sv4.x - m) : 0.f;
        const float p1 = (sv4.y > -1e29f) ? __expf(sv4.y - m) : 0.f;
        const float p2 = (sv4.z > -1e29f) ? __expf(sv4.z - m) : 0.f;
        const float p3 = (sv4.w > -1e29f) ? __expf(sv4.w - m) : 0.f;
        sum += (p0 + p1) + (p2 + p3);
        aw = fmaf(p0, fabsf(bf16_to_f32(w4.x)), aw);
        aw = fmaf(p1, fabsf(bf16_to_f32(w4.y)), aw);
        aw = fmaf(p2, fabsf(bf16_to_f32(w4.z)), aw);
        aw = fmaf(p3, fabsf(bf16_to_f32(w4.w)), aw);
        const float4 v0 = *(const float4*)&vh[(j0 + 0) * CH];
        const float4 v1 = *(const float4*)&vh[(j0 + 1) * CH];
        const float4 v2 = *(const float4*)&vh[(j0 + 2) * CH];
        const float4 v3 = *(const float4*)&vh[(j0 + 3) * CH];
        o0 = fmaf(p0, v0.x, o0); o1 = fmaf(p0, v0.y, o1); o2 = fmaf(p0, v0.z, o2); o3 = fmaf(p0, v0.w, o3);
        o0 = fmaf(p1, v1.x, o0); o1 = fmaf(p1, v1.y, o1); o2 = fmaf(p1, v1.z, o2); o3 = fmaf(p1, v1.w, o3);
        o0 = fmaf(p2, v2.x, o0); o1 = fmaf(p2, v2.y, o1); o2 = fmaf(p2, v2.z, o2); o3 = fmaf(p2, v2.w, o3);
        o0 = fmaf(p3, v3.x, o0); o1 = fmaf(p3, v3.y, o1); o2 = fmaf(p3, v3.z, o2); o3 = fmaf(p3, v3.w, o3);
    }
    #pragma unroll
    for (int off = 4; off <= 16; off <<= 1) {
        o0  += __shfl_xor(o0, off);
        o1  += __shfl_xor(o1, off);
        o2  += __shfl_xor(o2, off);
        o3  += __shfl_xor(o3, off);
        sum += __shfl_xor(sum, off);
        aw  += __shfl_xor(aw, off);
    }
    if (jb == 0) {
        const float inv = live ? 1.f / sum : 0.f;
        const float awv = aw * inv;
        const int idx = (i0 + i3) * HD + h * CH + c4 * 4;
        const float4 we4 = *(const float4*)&We[h * CH + c4 * 4];
        const float4 xo = *(const float4*)&x[idx];
        const float4 so = *(const float4*)&skip[idx];
        float4 o;
        o.x = xo.x + so.x + o0 * inv + awv * we4.x;
        o.y = xo.y + so.y + o1 * inv + awv * we4.y;
        o.z = xo.z + so.z + o2 * inv + awv * we4.z;
        o.w = xo.w + so.w + o3 * inv + awv * we4.w;
        *(float4*)&x[idx] = o;       // slice owned exclusively by this block
    }
}

// ---------------- launch ----------------
extern "C" void kernel_launch(void* const* d_in, const int* in_sizes, int n_in,
                              void* d_out, int out_size, void* d_ws, size_t ws_size,
                              hipStream_t stream) {
    const float* ent = (const float*)d_in[2];
    const float* W1  = (const float*)d_in[3];
    const float* b1  = (const float*)d_in[4];
    const float* W2  = (const float*)d_in[5];
    const float* b2  = (const float*)d_in[6];
    const float* Wq  = (const float*)d_in[7];
    const float* bq  = (const float*)d_in[8];
    const float* Wk  = (const float*)d_in[9];
    const float* bk  = (const float*)d_in[10];
    const float* Wv  = (const float*)d_in[11];
    const float* bv  = (const float*)d_in[12];
    const float* We  = (const float*)d_in[13];
    const float* Ws  = (const float*)d_in[14];
    const float* bs  = (const float*)d_in[15];

    unsigned short* wm = (unsigned short*)d_ws;   // [1024][1024] bf16, sign = mask (2 MB)
    float* fb = (float*)d_ws + (NN * NN / 2);     // float area after wm
    float* q  = fb;                               // [8][1024][16]  (reused as 'a' before layers)
    float* k  = q + NN * HD;                      //                (reused as 'b')
    float* v  = k + NN * HD;                      // [8][1024][16]
    float* sk = v + NN * HD;
    float* x  = (float*)d_out;                    // running entity state

    hipMemcpyAsync(x, ent, NN * HD * sizeof(float), hipMemcpyDeviceToDevice, stream);

    k_edge_ab<<<dim3(NN / ABM, 2), 256, 0, stream>>>(ent, W1, b1, q /*a*/, k /*b*/);
    k_edge_w<<<dim3(32, 64), 256, 0, stream>>>(q, k, W2, b2, wm);

    for (int l = 0; l < NLAYERS; ++l) {
        k_proj<<<dim3(NN / PBM, 4), 256, 0, stream>>>(x,
            Wq + l * HD * HD, bq + l * HD, Wk + l * HD * HD, bk + l * HD,
            Wv + l * HD * HD, bv + l * HD, Ws + l * HD * HD, bs + l * HD,
            q, k, v, sk);
        k_attn<<<dim3(NH, NN / TT), 256, 0, stream>>>(q, k, v, sk, wm, We + l * HD, x);
    }
}

// Round 8
// 131.945 us; speedup vs baseline: 1.6490x; 1.0048x over previous
//
#include <hip/hip_runtime.h>
#include <math.h>

#define NN 1024     // entities
#define HD 128      // hidden dim
#define NH 8        // heads
#define CH 16       // dim per head
#define NLAYERS 3

#define TT 8        // targets per attention block
#define SF 1040     // s_tile f32 row stride: 4160B; mod 128B = 64 -> adjacent rows shift 16 banks (2-way, free)
#define ALP 130     // al row stride (floats): 130%32=2 -> f2 reads across 32 rows hit 16 banks 2-way (free)
#define PBM 4       // k_proj rows per block
#define ABM 2       // k_edge_ab rows per block

__device__ __forceinline__ float bf16_to_f32(unsigned short u) {
    union { unsigned int i; float f; } x; x.i = ((unsigned int)u) << 16; return x.f;
}
__device__ __forceinline__ unsigned short f32_to_bf16(float f) {
    union { float f; unsigned int i; } x; x.f = f;
    const unsigned int r = x.i + 0x7FFFu + ((x.i >> 16) & 1u);   // RNE
    return (unsigned short)(r >> 16);
}

// ---------------- K1: a = x@W1[:128], b = x@W1[128:] + b1; by==0 also copies x -> xout ----------------
__global__ __launch_bounds__(256) void k_edge_ab(
        const float* __restrict__ x, const float* __restrict__ W1,
        const float* __restrict__ b1, float* __restrict__ a, float* __restrict__ b,
        float* __restrict__ xout) {
    __shared__ float xt[HD][ABM];        // x transposed: xt[kk][r]
    __shared__ float red[2][ABM][HD];    // kk-group partials
    const int r0 = blockIdx.x * ABM;
    const int cb = blockIdx.y;           // 0 -> a, 1 -> b
    const int t  = threadIdx.x;
    {
        const float xv = x[(r0 + (t >> 7)) * HD + (t & 127)];
        xt[t & 127][t >> 7] = xv;
        if (cb == 0) xout[(r0 + (t >> 7)) * HD + (t & 127)] = xv;   // fused x init
    }
    __syncthreads();
    const int c = t & 127, g = t >> 7;   // col, kk-group
    const float* wp = W1 + cb * HD * HD + g * 64 * HD + c;
    const float* xp = &xt[g * 64][0];
    float a0 = 0.f, a1 = 0.f;
    #pragma unroll 8
    for (int kk = 0; kk < 64; ++kk) {
        const float wv = wp[kk * HD];                         // coalesced 256B/wave
        const float2 xv = *(const float2*)&xp[kk * ABM];      // uniform ds_read_b64 (broadcast)
        a0 = fmaf(xv.x, wv, a0);
        a1 = fmaf(xv.y, wv, a1);
    }
    red[g][0][c] = a0; red[g][1][c] = a1;
    __syncthreads();
    if (t < HD) {
        float* dst = cb ? b : a;
        const float bias = cb ? b1[t] : 0.f;                  // fold b1 into b
        #pragma unroll
        for (int r = 0; r < ABM; ++r)
            dst[(r0 + r) * HD + t] = red[0][r][t] + red[1][r][t] + bias;
    }
}

// ---------------- K2: wm[t][s] = bf16( sign(mask) * sigmoid(logit[s][t]) ) ----------------
__global__ __launch_bounds__(256) void k_edge_w(
        const float* __restrict__ a, const float* __restrict__ bb,
        const float* __restrict__ W2, const float* __restrict__ b2,
        unsigned short* __restrict__ wm) {
    __shared__ float al[32][ALP];
    __shared__ float bl[16][HD];
    const int t = threadIdx.x;
    const int s0 = blockIdx.x * 32, t0 = blockIdx.y * 16;
    for (int ii = t; ii < 2048; ii += 256) {
        const int row = ii >> 6, col = (ii & 63) * 2;
        *(float2*)&al[row][col] = *(const float2*)&a[(s0 + row) * HD + col];
    }
    for (int ii = t; ii < 512; ii += 256) {
        const int row = ii >> 5, col = (ii & 31) * 4;
        *(float4*)&bl[row][col] = *(const float4*)&bb[(t0 + row) * HD + col];
    }
    __syncthreads();
    const int s = t & 31, tt = t >> 5;
    float acc0 = 0.f, acc1 = 0.f;
    #pragma unroll 2
    for (int h4 = 0; h4 < HD; h4 += 4) {
        const float4 w2 = *(const float4*)&W2[h4];          // uniform -> s_load_dwordx4
        const float2 avA = *(const float2*)&al[s][h4];
        const float2 avB = *(const float2*)&al[s][h4 + 2];
        const float4 b0v = *(const float4*)&bl[tt][h4];
        const float4 b1v = *(const float4*)&bl[tt + 8][h4];
        acc0 = fmaf(fmaxf(avA.x + b0v.x, 0.f), w2.x, acc0);
        acc0 = fmaf(fmaxf(avA.y + b0v.y, 0.f), w2.y, acc0);
        acc0 = fmaf(fmaxf(avB.x + b0v.z, 0.f), w2.z, acc0);
        acc0 = fmaf(fmaxf(avB.y + b0v.w, 0.f), w2.w, acc0);
        acc1 = fmaf(fmaxf(avA.x + b1v.x, 0.f), w2.x, acc1);
        acc1 = fmaf(fmaxf(avA.y + b1v.y, 0.f), w2.y, acc1);
        acc1 = fmaf(fmaxf(avB.x + b1v.z, 0.f), w2.z, acc1);
        acc1 = fmaf(fmaxf(avB.y + b1v.w, 0.f), w2.w, acc1);
    }
    const float bias = b2[0];
    const float l0 = acc0 + bias, l1 = acc1 + bias;
    const float w0 = 1.f / (1.f + __expf(-l0));
    const float w1 = 1.f / (1.f + __expf(-l1));
    wm[(t0 + tt    ) * NN + s0 + s] = f32_to_bf16((l0 > 0.f) ? w0 : -w0);   // sign encodes mask
    wm[(t0 + tt + 8) * NN + s0 + s] = f32_to_bf16((l1 > 0.f) ? w1 : -w1);
}

// ---------------- K3: projections q,k,v ([h][n][c]) + skip ----------------
// grid (NN/PBM, 4): by selects matrix {Wq,Wk,Wv,Ws}. 1024 blocks, kk-split x2.
__global__ __launch_bounds__(256) void k_proj(
        const float* __restrict__ x,
        const float* __restrict__ Wq, const float* __restrict__ bq,
        const float* __restrict__ Wk, const float* __restrict__ bk,
        const float* __restrict__ Wv, const float* __restrict__ bv,
        const float* __restrict__ Wsk, const float* __restrict__ bsk,
        float* __restrict__ q, float* __restrict__ k,
        float* __restrict__ v, float* __restrict__ skip) {
    __shared__ float xt[HD][PBM];        // x transposed: xt[kk][r]
    __shared__ float red[2][PBM][HD];    // kk-group partials
    const int r0 = blockIdx.x * PBM;
    const int cb = blockIdx.y;           // 0..3 -> q,k,v,skip
    const int t  = threadIdx.x;
    {   // stage 4x128 transposed (one-time; write conflicts negligible)
        const int r = t >> 6, c2 = (t & 63) * 2;
        const float2 xv = *(const float2*)&x[(r0 + r) * HD + c2];
        xt[c2][r] = xv.x; xt[c2 + 1][r] = xv.y;
    }
    __syncthreads();
    const int c = t & 127, g = t >> 7;   // col within matrix, kk-group
    const float* W = (cb == 0) ? Wq : (cb == 1) ? Wk : (cb == 2) ? Wv : Wsk;
    const float* wp = W + g * 64 * HD + c;
    const float* xp = &xt[g * 64][0];
    float a0 = 0.f, a1 = 0.f, a2 = 0.f, a3 = 0.f;
    #pragma unroll 8
    for (int kk = 0; kk < 64; ++kk) {
        const float wv = wp[kk * HD];                         // coalesced 256B/wave
        const float4 xv = *(const float4*)&xp[kk * PBM];      // uniform ds_read_b128 (broadcast)
        a0 = fmaf(xv.x, wv, a0);
        a1 = fmaf(xv.y, wv, a1);
        a2 = fmaf(xv.z, wv, a2);
        a3 = fmaf(xv.w, wv, a3);
    }
    red[g][0][c] = a0; red[g][1][c] = a1; red[g][2][c] = a2; red[g][3][c] = a3;
    __syncthreads();
    if (t < HD) {
        const float* bptr = (cb == 0) ? bq : (cb == 1) ? bk : (cb == 2) ? bv : bsk;
        const float bias = bptr[t];
        #pragma unroll
        for (int r = 0; r < PBM; ++r) {
            const float val = red[0][r][t] + red[1][r][t] + bias;
            const int row = r0 + r;
            if (cb == 3) {
                skip[row * HD + t] = val;
            } else {
                const int hnc = (t >> 4) * (NN * CH) + row * CH + (t & 15);
                ((cb == 0) ? q : (cb == 1) ? k : v)[hnc] = val;
            }
        }
    }
}

// ---------------- K4: fused attention, one (head, 8-target tile); 2 barriers ----------------
__global__ __launch_bounds__(256) void k_attn(
        const float* __restrict__ q, const float* __restrict__ k,
        const float* __restrict__ v, const float* __restrict__ skip,
        const unsigned short* __restrict__ wm, const float* __restrict__ We,
        float* __restrict__ x) {
    __shared__ float s_tile[TT][SF];   // 33.3 KB
    __shared__ float q_l[TT][CH];      // q * 0.25 (scale folded)
    __shared__ float mpart[4][TT];     // per-wave partial row maxima
    const int h  = blockIdx.x;
    const int i0 = blockIdx.y * TT;
    const int t  = threadIdx.x;

    if (t < TT * CH) q_l[t >> 4][t & 15] = q[h * (NN * CH) + (i0 + (t >> 4)) * CH + (t & 15)] * 0.25f;
    __syncthreads();

    // ---- phase 1: logits + online row max. 2 groups x 128 threads; group g owns rows g*4..g*4+3.
    const int g  = t >> 7;             // 0/1
    const int lj = t & 127;
    float qr[4][CH], qe[4];
    #pragma unroll
    for (int i = 0; i < 4; ++i) {
        float sv = 0.f;
        #pragma unroll
        for (int c = 0; c < CH; ++c) {
            qr[i][c] = q_l[g * 4 + i][c];
            sv = fmaf(qr[i][c], We[h * CH + c], sv);   // We uniform -> scalar loads
        }
        qe[i] = sv;                    // carries the 0.25 scale
    }
    const float* kh = k + h * (NN * CH);
    float mloc[4] = {-1e30f, -1e30f, -1e30f, -1e30f};
    #pragma unroll 1
    for (int p = 0; p < 8; ++p) {
        const int j = lj + 128 * p;
        const float4* kp = (const float4*)(kh + j * CH);
        const float4 r0 = kp[0], r1 = kp[1], r2 = kp[2], r3 = kp[3];
        const float kr[CH] = {r0.x, r0.y, r0.z, r0.w, r1.x, r1.y, r1.z, r1.w,
                              r2.x, r2.y, r2.z, r2.w, r3.x, r3.y, r3.z, r3.w};
        #pragma unroll
        for (int i = 0; i < 4; ++i) {
            float dot = 0.f;
            #pragma unroll
            for (int c = 0; c < CH; ++c) dot = fmaf(qr[i][c], kr[c], dot);
            const float wv = bf16_to_f32(wm[(i0 + g * 4 + i) * NN + j]);   // sign = mask
            float sv = dot + qe[i] * fabsf(wv);
            sv = (wv > 0.f) ? sv : -1e30f;
            s_tile[g * 4 + i][j] = sv;
            mloc[i] = fmaxf(mloc[i], sv);
        }
    }
    #pragma unroll
    for (int off = 1; off < 64; off <<= 1) {
        #pragma unroll
        for (int i = 0; i < 4; ++i) mloc[i] = fmaxf(mloc[i], __shfl_xor(mloc[i], off));
    }
    if ((t & 63) == 0) {
        const int w = t >> 6;
        #pragma unroll
        for (int i = 0; i < 4; ++i) mpart[w][g * 4 + i] = mloc[i];
    }
    __syncthreads();

    // ---- phase 2: j-parallel PV. wave c4 owns c-quad; 64 lanes sweep j; v read ONCE per block. ----
    const int c4 = t >> 6;            // wave id = c-quad
    const int jl = t & 63;
    float mrow[8];
    #pragma unroll
    for (int i = 0; i < 4; ++i) {
        mrow[i]     = fmaxf(mpart[0][i],     mpart[1][i]);
        mrow[i + 4] = fmaxf(mpart[2][i + 4], mpart[3][i + 4]);
    }
    float4 o[8];
    float sum[8], aw[8];
    #pragma unroll
    for (int i = 0; i < 8; ++i) { o[i] = make_float4(0.f, 0.f, 0.f, 0.f); sum[i] = 0.f; aw[i] = 0.f; }
    const float* vh4 = v + h * (NN * CH) + c4 * 4;
    const unsigned short* wbase = wm + i0 * NN;
    #pragma unroll 2
    for (int it = 0; it < 16; ++it) {
        const int j = jl + 64 * it;
        const float4 vv = *(const float4*)&vh4[j * CH];
        #pragma unroll
        for (int i = 0; i < 8; ++i) {
            const float sv = s_tile[i][j];                       // 256B contiguous across lanes
            const float pv = (sv > -1e29f) ? __expf(sv - mrow[i]) : 0.f;
            const float wv = fabsf(bf16_to_f32(wbase[i * NN + j]));
            sum[i] += pv;
            aw[i]  = fmaf(pv, wv, aw[i]);
            o[i].x = fmaf(pv, vv.x, o[i].x);
            o[i].y = fmaf(pv, vv.y, o[i].y);
            o[i].z = fmaf(pv, vv.z, o[i].z);
            o[i].w = fmaf(pv, vv.w, o[i].w);
        }
    }
    #pragma unroll
    for (int off = 1; off < 64; off <<= 1) {
        #pragma unroll
        for (int i = 0; i < 8; ++i) {
            o[i].x += __shfl_xor(o[i].x, off);
            o[i].y += __shfl_xor(o[i].y, off);
            o[i].z += __shfl_xor(o[i].z, off);
            o[i].w += __shfl_xor(o[i].w, off);
            sum[i] += __shfl_xor(sum[i], off);
            aw[i]  += __shfl_xor(aw[i], off);
        }
    }
    #pragma unroll
    for (int i = 0; i < 8; ++i) {
        if (jl == i) {                                           // lane i writes row i, c-slice c4
            const float inv = (mrow[i] > -1e29f) ? 1.f / sum[i] : 0.f;
            const float awv = aw[i] * inv;
            const int idx = (i0 + i) * HD + h * CH + c4 * 4;
            const float4 we4 = *(const float4*)&We[h * CH + c4 * 4];
            const float4 xo = *(const float4*)&x[idx];
            const float4 so = *(const float4*)&skip[idx];
            float4 ov;
            ov.x = xo.x + so.x + o[i].x * inv + awv * we4.x;
            ov.y = xo.y + so.y + o[i].y * inv + awv * we4.y;
            ov.z = xo.z + so.z + o[i].z * inv + awv * we4.z;
            ov.w = xo.w + so.w + o[i].w * inv + awv * we4.w;
            *(float4*)&x[idx] = ov;      // slice owned exclusively by this block
        }
    }
}

// ---------------- launch ----------------
extern "C" void kernel_launch(void* const* d_in, const int* in_sizes, int n_in,
                              void* d_out, int out_size, void* d_ws, size_t ws_size,
                              hipStream_t stream) {
    const float* ent = (const float*)d_in[2];
    const float* W1  = (const float*)d_in[3];
    const float* b1  = (const float*)d_in[4];
    const float* W2  = (const float*)d_in[5];
    const float* b2  = (const float*)d_in[6];
    const float* Wq  = (const float*)d_in[7];
    const float* bq  = (const float*)d_in[8];
    const float* Wk  = (const float*)d_in[9];
    const float* bk  = (const float*)d_in[10];
    const float* Wv  = (const float*)d_in[11];
    const float* bv  = (const float*)d_in[12];
    const float* We  = (const float*)d_in[13];
    const float* Ws  = (const float*)d_in[14];
    const float* bs  = (const float*)d_in[15];

    unsigned short* wm = (unsigned short*)d_ws;   // [1024][1024] bf16, sign = mask (2 MB)
    float* fb = (float*)d_ws + (NN * NN / 2);     // float area after wm
    float* q  = fb;                               // [8][1024][16]  (reused as 'a' before layers)
    float* k  = q + NN * HD;                      //                (reused as 'b')
    float* v  = k + NN * HD;                      // [8][1024][16]
    float* sk = v + NN * HD;
    float* x  = (float*)d_out;                    // running entity state

    k_edge_ab<<<dim3(NN / ABM, 2), 256, 0, stream>>>(ent, W1, b1, q /*a*/, k /*b*/, x);
    k_edge_w<<<dim3(32, 64), 256, 0, stream>>>(q, k, W2, b2, wm);

    for (int l = 0; l < NLAYERS; ++l) {
        k_proj<<<dim3(NN / PBM, 4), 256, 0, stream>>>(x,
            Wq + l * HD * HD, bq + l * HD, Wk + l * HD * HD, bk + l * HD,
            Wv + l * HD * HD, bv + l * HD, Ws + l * HD * HD, bs + l * HD,
            q, k, v, sk);
        k_attn<<<dim3(NH, NN / TT), 256, 0, stream>>>(q, k, v, sk, wm, We + l * HD, x);
    }
}

// Round 9
// 128.747 us; speedup vs baseline: 1.6900x; 1.0248x over previous
//
#include <hip/hip_runtime.h>
#include <math.h>

#define NN 1024     // entities
#define HD 128      // hidden dim
#define NH 8        // heads
#define CH 16       // dim per head
#define NLAYERS 3

#define TT 8        // targets per attention block
#define SF 1040     // s_tile f32 row stride: 4160B; mod 128B = 64 -> adjacent rows shift 16 banks (2-way, free)
#define ALP 130     // al row stride (floats): 130%32=2 -> f2 reads across 32 rows hit 16 banks 2-way (free)
#define PBM 4       // k_proj rows per block
#define ABM 2       // k_edge_ab rows per block

__device__ __forceinline__ float bf16_to_f32(unsigned short u) {
    union { unsigned int i; float f; } x; x.i = ((unsigned int)u) << 16; return x.f;
}
__device__ __forceinline__ unsigned short f32_to_bf16(float f) {
    union { float f; unsigned int i; } x; x.f = f;
    const unsigned int r = x.i + 0x7FFFu + ((x.i >> 16) & 1u);   // RNE
    return (unsigned short)(r >> 16);
}

// ---------------- K1: a = x@W1[:128], b = x@W1[128:] + b1; by==0 also copies x -> xout ----------------
__global__ __launch_bounds__(256) void k_edge_ab(
        const float* __restrict__ x, const float* __restrict__ W1,
        const float* __restrict__ b1, float* __restrict__ a, float* __restrict__ b,
        float* __restrict__ xout) {
    __shared__ float xt[HD][ABM];        // x transposed: xt[kk][r]
    __shared__ float red[2][ABM][HD];    // kk-group partials
    const int r0 = blockIdx.x * ABM;
    const int cb = blockIdx.y;           // 0 -> a, 1 -> b
    const int t  = threadIdx.x;
    {
        const float xv = x[(r0 + (t >> 7)) * HD + (t & 127)];
        xt[t & 127][t >> 7] = xv;
        if (cb == 0) xout[(r0 + (t >> 7)) * HD + (t & 127)] = xv;   // fused x init
    }
    __syncthreads();
    const int c = t & 127, g = t >> 7;   // col, kk-group
    const float* wp = W1 + cb * HD * HD + g * 64 * HD + c;
    const float* xp = &xt[g * 64][0];
    float a0 = 0.f, a1 = 0.f;
    #pragma unroll 8
    for (int kk = 0; kk < 64; ++kk) {
        const float wv = wp[kk * HD];                         // coalesced 256B/wave
        const float2 xv = *(const float2*)&xp[kk * ABM];      // uniform ds_read_b64 (broadcast)
        a0 = fmaf(xv.x, wv, a0);
        a1 = fmaf(xv.y, wv, a1);
    }
    red[g][0][c] = a0; red[g][1][c] = a1;
    __syncthreads();
    if (t < HD) {
        float* dst = cb ? b : a;
        const float bias = cb ? b1[t] : 0.f;                  // fold b1 into b
        #pragma unroll
        for (int r = 0; r < ABM; ++r)
            dst[(r0 + r) * HD + t] = red[0][r][t] + red[1][r][t] + bias;
    }
}

// ---------------- K2: wm[t][s] = bf16( sign(mask) * sigmoid(logit[s][t]) ) ----------------
__global__ __launch_bounds__(256) void k_edge_w(
        const float* __restrict__ a, const float* __restrict__ bb,
        const float* __restrict__ W2, const float* __restrict__ b2,
        unsigned short* __restrict__ wm) {
    __shared__ float al[32][ALP];
    __shared__ float bl[16][HD];
    const int t = threadIdx.x;
    const int s0 = blockIdx.x * 32, t0 = blockIdx.y * 16;
    for (int ii = t; ii < 2048; ii += 256) {
        const int row = ii >> 6, col = (ii & 63) * 2;
        *(float2*)&al[row][col] = *(const float2*)&a[(s0 + row) * HD + col];
    }
    for (int ii = t; ii < 512; ii += 256) {
        const int row = ii >> 5, col = (ii & 31) * 4;
        *(float4*)&bl[row][col] = *(const float4*)&bb[(t0 + row) * HD + col];
    }
    __syncthreads();
    const int s = t & 31, tt = t >> 5;
    float acc0 = 0.f, acc1 = 0.f;
    #pragma unroll 2
    for (int h4 = 0; h4 < HD; h4 += 4) {
        const float4 w2 = *(const float4*)&W2[h4];          // uniform -> s_load_dwordx4
        const float2 avA = *(const float2*)&al[s][h4];
        const float2 avB = *(const float2*)&al[s][h4 + 2];
        const float4 b0v = *(const float4*)&bl[tt][h4];
        const float4 b1v = *(const float4*)&bl[tt + 8][h4];
        acc0 = fmaf(fmaxf(avA.x + b0v.x, 0.f), w2.x, acc0);
        acc0 = fmaf(fmaxf(avA.y + b0v.y, 0.f), w2.y, acc0);
        acc0 = fmaf(fmaxf(avB.x + b0v.z, 0.f), w2.z, acc0);
        acc0 = fmaf(fmaxf(avB.y + b0v.w, 0.f), w2.w, acc0);
        acc1 = fmaf(fmaxf(avA.x + b1v.x, 0.f), w2.x, acc1);
        acc1 = fmaf(fmaxf(avA.y + b1v.y, 0.f), w2.y, acc1);
        acc1 = fmaf(fmaxf(avB.x + b1v.z, 0.f), w2.z, acc1);
        acc1 = fmaf(fmaxf(avB.y + b1v.w, 0.f), w2.w, acc1);
    }
    const float bias = b2[0];
    const float l0 = acc0 + bias, l1 = acc1 + bias;
    const float w0 = 1.f / (1.f + __expf(-l0));
    const float w1 = 1.f / (1.f + __expf(-l1));
    wm[(t0 + tt    ) * NN + s0 + s] = f32_to_bf16((l0 > 0.f) ? w0 : -w0);   // sign encodes mask
    wm[(t0 + tt + 8) * NN + s0 + s] = f32_to_bf16((l1 > 0.f) ? w1 : -w1);
}

// ---------------- K3: projections q,k,v ([h][n][c]) + skip ----------------
// grid (NN/PBM, 4): by selects matrix {Wq,Wk,Wv,Ws}. 1024 blocks, kk-split x2.
__global__ __launch_bounds__(256) void k_proj(
        const float* __restrict__ x,
        const float* __restrict__ Wq, const float* __restrict__ bq,
        const float* __restrict__ Wk, const float* __restrict__ bk,
        const float* __restrict__ Wv, const float* __restrict__ bv,
        const float* __restrict__ Wsk, const float* __restrict__ bsk,
        float* __restrict__ q, float* __restrict__ k,
        float* __restrict__ v, float* __restrict__ skip) {
    __shared__ float xt[HD][PBM];        // x transposed: xt[kk][r]
    __shared__ float red[2][PBM][HD];    // kk-group partials
    const int r0 = blockIdx.x * PBM;
    const int cb = blockIdx.y;           // 0..3 -> q,k,v,skip
    const int t  = threadIdx.x;
    {   // stage 4x128 transposed (one-time; write conflicts negligible)
        const int r = t >> 6, c2 = (t & 63) * 2;
        const float2 xv = *(const float2*)&x[(r0 + r) * HD + c2];
        xt[c2][r] = xv.x; xt[c2 + 1][r] = xv.y;
    }
    __syncthreads();
    const int c = t & 127, g = t >> 7;   // col within matrix, kk-group
    const float* W = (cb == 0) ? Wq : (cb == 1) ? Wk : (cb == 2) ? Wv : Wsk;
    const float* wp = W + g * 64 * HD + c;
    const float* xp = &xt[g * 64][0];
    float a0 = 0.f, a1 = 0.f, a2 = 0.f, a3 = 0.f;
    #pragma unroll 8
    for (int kk = 0; kk < 64; ++kk) {
        const float wv = wp[kk * HD];                         // coalesced 256B/wave
        const float4 xv = *(const float4*)&xp[kk * PBM];      // uniform ds_read_b128 (broadcast)
        a0 = fmaf(xv.x, wv, a0);
        a1 = fmaf(xv.y, wv, a1);
        a2 = fmaf(xv.z, wv, a2);
        a3 = fmaf(xv.w, wv, a3);
    }
    red[g][0][c] = a0; red[g][1][c] = a1; red[g][2][c] = a2; red[g][3][c] = a3;
    __syncthreads();
    if (t < HD) {
        const float* bptr = (cb == 0) ? bq : (cb == 1) ? bk : (cb == 2) ? bv : bsk;
        const float bias = bptr[t];
        #pragma unroll
        for (int r = 0; r < PBM; ++r) {
            const float val = red[0][r][t] + red[1][r][t] + bias;
            const int row = r0 + r;
            if (cb == 3) {
                skip[row * HD + t] = val;
            } else {
                const int hnc = (t >> 4) * (NN * CH) + row * CH + (t & 15);
                ((cb == 0) ? q : (cb == 1) ? k : v)[hnc] = val;
            }
        }
    }
}

// ---------------- K4: fused attention, one (head, 8-target tile); 2 barriers ----------------
__global__ __launch_bounds__(256) void k_attn(
        const float* __restrict__ q, const float* __restrict__ k,
        const float* __restrict__ v, const float* __restrict__ skip,
        const unsigned short* __restrict__ wm, const float* __restrict__ We,
        float* __restrict__ x) {
    __shared__ float s_tile[TT][SF];   // 33.3 KB
    __shared__ float q_l[TT][CH];      // q * 0.25 (scale folded)
    __shared__ float mpart[4][TT];     // per-wave partial row maxima
    const int h  = blockIdx.x;
    const int i0 = blockIdx.y * TT;
    const int t  = threadIdx.x;

    if (t < TT * CH) q_l[t >> 4][t & 15] = q[h * (NN * CH) + (i0 + (t >> 4)) * CH + (t & 15)] * 0.25f;
    __syncthreads();

    // ---- phase 1: logits + online row max. 2 groups x 128 threads; group g owns rows g*4..g*4+3.
    const int g  = t >> 7;             // 0/1
    const int lj = t & 127;
    float qr[4][CH], qe[4];
    #pragma unroll
    for (int i = 0; i < 4; ++i) {
        float sv = 0.f;
        #pragma unroll
        for (int c = 0; c < CH; ++c) {
            qr[i][c] = q_l[g * 4 + i][c];
            sv = fmaf(qr[i][c], We[h * CH + c], sv);   // We uniform -> scalar loads
        }
        qe[i] = sv;                    // carries the 0.25 scale
    }
    const float* kh = k + h * (NN * CH);
    float mloc[4] = {-1e30f, -1e30f, -1e30f, -1e30f};
    #pragma unroll 1
    for (int p = 0; p < 8; ++p) {
        const int j = lj + 128 * p;
        const float4* kp = (const float4*)(kh + j * CH);
        const float4 r0 = kp[0], r1 = kp[1], r2 = kp[2], r3 = kp[3];
        const float kr[CH] = {r0.x, r0.y, r0.z, r0.w, r1.x, r1.y, r1.z, r1.w,
                              r2.x, r2.y, r2.z, r2.w, r3.x, r3.y, r3.z, r3.w};
        #pragma unroll
        for (int i = 0; i < 4; ++i) {
            float dot = 0.f;
            #pragma unroll
            for (int c = 0; c < CH; ++c) dot = fmaf(qr[i][c], kr[c], dot);
            const float wv = bf16_to_f32(wm[(i0 + g * 4 + i) * NN + j]);   // sign = mask
            float sv = dot + qe[i] * fabsf(wv);
            sv = (wv > 0.f) ? sv : -1e30f;
            s_tile[g * 4 + i][j] = sv;
            mloc[i] = fmaxf(mloc[i], sv);
        }
    }
    #pragma unroll
    for (int off = 1; off < 64; off <<= 1) {
        #pragma unroll
        for (int i = 0; i < 4; ++i) mloc[i] = fmaxf(mloc[i], __shfl_xor(mloc[i], off));
    }
    if ((t & 63) == 0) {
        const int w = t >> 6;
        #pragma unroll
        for (int i = 0; i < 4; ++i) mpart[w][g * 4 + i] = mloc[i];
    }
    __syncthreads();

    // ---- phase 2 (fused): exp + sum + aw + PV in one scan. thread = (i3, jb, c4). ----
    const int i3 = t >> 5, jb = (t >> 2) & 7, c4 = t & 3;
    const int gr = i3 >> 2;
    const float m = fmaxf(mpart[2 * gr][i3], mpart[2 * gr + 1][i3]);
    const bool live = m > -1e29f;
    const float* vh = v + h * (NN * CH) + c4 * 4;
    const unsigned short* wrow = wm + (i0 + i3) * NN;
    float o0 = 0.f, o1 = 0.f, o2 = 0.f, o3 = 0.f, sum = 0.f, aw = 0.f;
    #pragma unroll 2
    for (int gg = 0; gg < 32; ++gg) {
        const int j0 = jb * 4 + 32 * gg;
        const float4 sv4 = *(const float4*)&s_tile[i3][j0];
        const ushort4 w4 = *(const ushort4*)&wrow[j0];
        const float p0 = (sv4.x > -1e29f) ? __expf(sv4.x - m) : 0.f;
        const float p1 = (sv4.y > -1e29f) ? __expf(sv4.y - m) : 0.f;
        const float p2 = (sv4.z > -1e29f) ? __expf(sv4.z - m) : 0.f;
        const float p3 = (sv4.w > -1e29f) ? __expf(sv4.w - m) : 0.f;
        sum += (p0 + p1) + (p2 + p3);
        aw = fmaf(p0, fabsf(bf16_to_f32(w4.x)), aw);
        aw = fmaf(p1, fabsf(bf16_to_f32(w4.y)), aw);
        aw = fmaf(p2, fabsf(bf16_to_f32(w4.z)), aw);
        aw = fmaf(p3, fabsf(bf16_to_f32(w4.w)), aw);
        const float4 v0 = *(const float4*)&vh[(j0 + 0) * CH];
        const float4 v1 = *(const float4*)&vh[(j0 + 1) * CH];
        const float4 v2 = *(const float4*)&vh[(j0 + 2) * CH];
        const float4 v3 = *(const float4*)&vh[(j0 + 3) * CH];
        o0 = fmaf(p0, v0.x, o0); o1 = fmaf(p0, v0.y, o1); o2 = fmaf(p0, v0.z, o2); o3 = fmaf(p0, v0.w, o3);
        o0 = fmaf(p1, v1.x, o0); o1 = fmaf(p1, v1.y, o1); o2 = fmaf(p1, v1.z, o2); o3 = fmaf(p1, v1.w, o3);
        o0 = fmaf(p2, v2.x, o0); o1 = fmaf(p2, v2.y, o1); o2 = fmaf(p2, v2.z, o2); o3 = fmaf(p2, v2.w, o3);
        o0 = fmaf(p3, v3.x, o0); o1 = fmaf(p3, v3.y, o1); o2 = fmaf(p3, v3.z, o2); o3 = fmaf(p3, v3.w, o3);
    }
    #pragma unroll
    for (int off = 4; off <= 16; off <<= 1) {
        o0  += __shfl_xor(o0, off);
        o1  += __shfl_xor(o1, off);
        o2  += __shfl_xor(o2, off);
        o3  += __shfl_xor(o3, off);
        sum += __shfl_xor(sum, off);
        aw  += __shfl_xor(aw, off);
    }
    if (jb == 0) {
        const float inv = live ? 1.f / sum : 0.f;
        const float awv = aw * inv;
        const int idx = (i0 + i3) * HD + h * CH + c4 * 4;
        const float4 we4 = *(const float4*)&We[h * CH + c4 * 4];
        const float4 xo = *(const float4*)&x[idx];
        const float4 so = *(const float4*)&skip[idx];
        float4 o;
        o.x = xo.x + so.x + o0 * inv + awv * we4.x;
        o.y = xo.y + so.y + o1 * inv + awv * we4.y;
        o.z = xo.z + so.z + o2 * inv + awv * we4.z;
        o.w = xo.w + so.w + o3 * inv + awv * we4.w;
        *(float4*)&x[idx] = o;       // slice owned exclusively by this block
    }
}

// ---------------- launch ----------------
extern "C" void kernel_launch(void* const* d_in, const int* in_sizes, int n_in,
                              void* d_out, int out_size, void* d_ws, size_t ws_size,
                              hipStream_t stream) {
    const float* ent = (const float*)d_in[2];
    const float* W1  = (const float*)d_in[3];
    const float* b1  = (const float*)d_in[4];
    const float* W2  = (const float*)d_in[5];
    const float* b2  = (const float*)d_in[6];
    const float* Wq  = (const float*)d_in[7];
    const float* bq  = (const float*)d_in[8];
    const float* Wk  = (const float*)d_in[9];
    const float* bk  = (const float*)d_in[10];
    const float* Wv  = (const float*)d_in[11];
    const float* bv  = (const float*)d_in[12];
    const float* We  = (const float*)d_in[13];
    const float* Ws  = (const float*)d_in[14];
    const float* bs  = (const float*)d_in[15];

    unsigned short* wm = (unsigned short*)d_ws;   // [1024][1024] bf16, sign = mask (2 MB)
    float* fb = (float*)d_ws + (NN * NN / 2);     // float area after wm
    float* q  = fb;                               // [8][1024][16]  (reused as 'a' before layers)
    float* k  = q + NN * HD;                      //                (reused as 'b')
    float* v  = k + NN * HD;                      // [8][1024][16]
    float* sk = v + NN * HD;
    float* x  = (float*)d_out;                    // running entity state

    k_edge_ab<<<dim3(NN / ABM, 2), 256, 0, stream>>>(ent, W1, b1, q /*a*/, k /*b*/, x);
    k_edge_w<<<dim3(32, 64), 256, 0, stream>>>(q, k, W2, b2, wm);

    for (int l = 0; l < NLAYERS; ++l) {
        k_proj<<<dim3(NN / PBM, 4), 256, 0, stream>>>(x,
            Wq + l * HD * HD, bq + l * HD, Wk + l * HD * HD, bk + l * HD,
            Wv + l * HD * HD, bv + l * HD, Ws + l * HD * HD, bs + l * HD,
            q, k, v, sk);
        k_attn<<<dim3(NH, NN / TT), 256, 0, stream>>>(q, k, v, sk, wm, We + l * HD, x);
    }
}